// Round 1
// baseline (164.489 us; speedup 1.0000x reference)
//
#include <hip/hip_runtime.h>
#include <math.h>

#define B 256
#define S 512
#define H 768
#define NCH 8
#define SCH (S / NCH)   // 64 tokens per chunk
#define NSMALL 64       // n = B/4

__device__ __forceinline__ float waveReduceSum(float v) {
    v += __shfl_down(v, 32);
    v += __shfl_down(v, 16);
    v += __shfl_down(v, 8);
    v += __shfl_down(v, 4);
    v += __shfl_down(v, 2);
    v += __shfl_down(v, 1);
    return v;
}

__device__ __forceinline__ float waveReduceMax(float v) {
    v = fmaxf(v, __shfl_down(v, 32));
    v = fmaxf(v, __shfl_down(v, 16));
    v = fmaxf(v, __shfl_down(v, 8));
    v = fmaxf(v, __shfl_down(v, 4));
    v = fmaxf(v, __shfl_down(v, 2));
    v = fmaxf(v, __shfl_down(v, 1));
    return v;
}

// Kernel 1: partial token-sum per (batch, s-chunk). 192 threads = 192 float4
// columns covering H=768. Coalesced: a wave reads 1 KB contiguous per instr.
__global__ void pool_partial_k(const float* __restrict__ lhs,
                               float* __restrict__ part) {
    const int b = blockIdx.x;   // 0..255
    const int c = blockIdx.y;   // 0..7
    const int t = threadIdx.x;  // 0..191
    const float4* __restrict__ src =
        reinterpret_cast<const float4*>(lhs) + ((size_t)b * S + (size_t)c * SCH) * (H / 4);
    float4 acc = make_float4(0.f, 0.f, 0.f, 0.f);
#pragma unroll 8
    for (int s = 0; s < SCH; ++s) {
        float4 v = src[(size_t)s * (H / 4) + t];
        acc.x += v.x; acc.y += v.y; acc.z += v.z; acc.w += v.w;
    }
    float4* dst = reinterpret_cast<float4*>(part) + ((size_t)c * B + b) * (H / 4);
    dst[t] = acc;
}

// Kernel 2: reduce the 8 partials, divide by mask-sum (faithful to ref),
// L2-normalize the pooled row -> z[b][h].
__global__ void pool_norm_k(const float* __restrict__ part,
                            const float* __restrict__ mask,
                            float* __restrict__ z) {
    const int b = blockIdx.x;   // 0..255
    const int t = threadIdx.x;  // 0..255
    __shared__ float sm[4];

    // mask.sum over 512 tokens
    float mv = mask[(size_t)b * S + t] + mask[(size_t)b * S + 256 + t];
    float w = waveReduceSum(mv);
    if ((t & 63) == 0) sm[t >> 6] = w;
    __syncthreads();
    const float msum = sm[0] + sm[1] + sm[2] + sm[3];
    __syncthreads();

    // pooled: thread t owns h = t, t+256, t+512
    float p0 = 0.f, p1 = 0.f, p2 = 0.f;
    for (int c = 0; c < NCH; ++c) {
        const float* pr = part + ((size_t)c * B + b) * H;
        p0 += pr[t];
        p1 += pr[t + 256];
        p2 += pr[t + 512];
    }
    const float inv_m = 1.0f / msum;
    p0 *= inv_m; p1 *= inv_m; p2 *= inv_m;

    float sq = p0 * p0 + p1 * p1 + p2 * p2;
    float ws2 = waveReduceSum(sq);
    if ((t & 63) == 0) sm[t >> 6] = ws2;
    __syncthreads();
    const float inv_n = 1.0f / sqrtf(sm[0] + sm[1] + sm[2] + sm[3]);

    z[(size_t)b * H + t]       = p0 * inv_n;
    z[(size_t)b * H + 256 + t] = p1 * inv_n;
    z[(size_t)b * H + 512 + t] = p2 * inv_n;
}

// Kernel 3: logits rows 0..63 only (rows >= n are dead in the reference).
// logits[i][j] = dot(z[i], z[j]) / TAU,  TAU = 0.5.
__global__ void logits_k(const float* __restrict__ z,
                         float* __restrict__ logits) {
    const int i = blockIdx.x;   // 0..63
    const int j = threadIdx.x;  // 0..255
    __shared__ float zi[H];
    zi[j]       = z[(size_t)i * H + j];
    zi[j + 256] = z[(size_t)i * H + 256 + j];
    zi[j + 512] = z[(size_t)i * H + 512 + j];
    __syncthreads();

    const float4* __restrict__ zj = reinterpret_cast<const float4*>(z + (size_t)j * H);
    const float4* zi4 = reinterpret_cast<const float4*>(zi);
    float d = 0.f;
#pragma unroll 4
    for (int k = 0; k < H / 4; ++k) {
        float4 a = zi4[k];
        float4 c = zj[k];
        d += a.x * c.x + a.y * c.y + a.z * c.z + a.w * c.w;
    }
    logits[(size_t)i * B + j] = d * 2.0f;  // / TAU
}

// Kernel 4: per-row masked logsumexp over all 256 cols, then upper-triangle
// pair sum over j in (i, 64). Single block, fixed-order reductions.
__global__ void loss_k(const float* __restrict__ logits,
                       float* __restrict__ out) {
    const int t = threadIdx.x;  // 0..255
    __shared__ float smax[4];
    __shared__ float ssum[4];
    __shared__ float stot[4];

    float acc = 0.f;
    for (int i = 0; i < NSMALL; ++i) {
        const float v = logits[(size_t)i * B + t];
        const float x = (t == i) ? -INFINITY : v;

        float m = waveReduceMax(x);
        if ((t & 63) == 0) smax[t >> 6] = m;
        __syncthreads();
        m = fmaxf(fmaxf(smax[0], smax[1]), fmaxf(smax[2], smax[3]));

        const float e = (t == i) ? 0.f : expf(x - m);
        float s = waveReduceSum(e);
        if ((t & 63) == 0) ssum[t >> 6] = s;
        __syncthreads();
        const float logden = logf(ssum[0] + ssum[1] + ssum[2] + ssum[3]) + m;

        if (t > i && t < NSMALL) acc += logden - v;
        __syncthreads();  // protect smax/ssum before next iteration overwrites
    }

    float tot = waveReduceSum(acc);
    if ((t & 63) == 0) stot[t >> 6] = tot;
    __syncthreads();
    if (t == 0) {
        out[0] = (-2.0f / (float)NSMALL) * (float)(NSMALL - 1) *
                 (stot[0] + stot[1] + stot[2] + stot[3]);
    }
}

extern "C" void kernel_launch(void* const* d_in, const int* in_sizes, int n_in,
                              void* d_out, int out_size, void* d_ws, size_t ws_size,
                              hipStream_t stream) {
    const float* lhs  = (const float*)d_in[0];   // [256,512,768] f32
    const float* mask = (const float*)d_in[1];   // [256,512] f32
    float* out = (float*)d_out;                  // scalar f32
    float* ws  = (float*)d_ws;

    float* part   = ws;                             // NCH*B*H   = 1,572,864 f
    float* z      = part + (size_t)NCH * B * H;     // B*H       =   196,608 f
    float* logits = z + (size_t)B * H;              // NSMALL*B  =    16,384 f

    pool_partial_k<<<dim3(B, NCH), 192, 0, stream>>>(lhs, part);
    pool_norm_k<<<B, 256, 0, stream>>>(part, mask, z);
    logits_k<<<NSMALL, 256, 0, stream>>>(z, logits);
    loss_k<<<1, 256, 0, stream>>>(logits, out);
}

// Round 2
// 106.808 us; speedup vs baseline: 1.5400x; 1.5400x over previous
//
#include <hip/hip_runtime.h>
#include <math.h>

#define B 256
#define S 512
#define H 768
#define NCH 8
#define SCH (S / NCH)   // 64 tokens per chunk
#define NSMALL 64       // n = B/4

__device__ __forceinline__ float waveReduceSum(float v) {
    v += __shfl_down(v, 32);
    v += __shfl_down(v, 16);
    v += __shfl_down(v, 8);
    v += __shfl_down(v, 4);
    v += __shfl_down(v, 2);
    v += __shfl_down(v, 1);
    return v;
}

__device__ __forceinline__ float waveReduceMax(float v) {
    v = fmaxf(v, __shfl_down(v, 32));
    v = fmaxf(v, __shfl_down(v, 16));
    v = fmaxf(v, __shfl_down(v, 8));
    v = fmaxf(v, __shfl_down(v, 4));
    v = fmaxf(v, __shfl_down(v, 2));
    v = fmaxf(v, __shfl_down(v, 1));
    return v;
}

// Kernel 1: partial token-sum per (batch, s-chunk). 192 threads = 192 float4
// columns covering H=768. Coalesced: a wave reads 1 KB contiguous per instr.
__global__ void pool_partial_k(const float* __restrict__ lhs,
                               float* __restrict__ part) {
    const int b = blockIdx.x;   // 0..255
    const int c = blockIdx.y;   // 0..7
    const int t = threadIdx.x;  // 0..191
    const float4* __restrict__ src =
        reinterpret_cast<const float4*>(lhs) + ((size_t)b * S + (size_t)c * SCH) * (H / 4);
    float4 acc = make_float4(0.f, 0.f, 0.f, 0.f);
#pragma unroll 16
    for (int s = 0; s < SCH; ++s) {
        float4 v = src[(size_t)s * (H / 4) + t];
        acc.x += v.x; acc.y += v.y; acc.z += v.z; acc.w += v.w;
    }
    float4* dst = reinterpret_cast<float4*>(part) + ((size_t)c * B + b) * (H / 4);
    dst[t] = acc;
}

// Kernel 2: reduce the 8 partials, divide by mask-sum (faithful to ref),
// L2-normalize the pooled row -> z[b][h].
__global__ void pool_norm_k(const float* __restrict__ part,
                            const float* __restrict__ mask,
                            float* __restrict__ z) {
    const int b = blockIdx.x;   // 0..255
    const int t = threadIdx.x;  // 0..255
    __shared__ float sm[4];

    // mask.sum over 512 tokens
    float mv = mask[(size_t)b * S + t] + mask[(size_t)b * S + 256 + t];
    float w = waveReduceSum(mv);
    if ((t & 63) == 0) sm[t >> 6] = w;
    __syncthreads();
    const float msum = sm[0] + sm[1] + sm[2] + sm[3];
    __syncthreads();

    // pooled: thread t owns h = t, t+256, t+512
    float p0 = 0.f, p1 = 0.f, p2 = 0.f;
    for (int c = 0; c < NCH; ++c) {
        const float* pr = part + ((size_t)c * B + b) * H;
        p0 += pr[t];
        p1 += pr[t + 256];
        p2 += pr[t + 512];
    }
    const float inv_m = 1.0f / msum;
    p0 *= inv_m; p1 *= inv_m; p2 *= inv_m;

    float sq = p0 * p0 + p1 * p1 + p2 * p2;
    float ws2 = waveReduceSum(sq);
    if ((t & 63) == 0) sm[t >> 6] = ws2;
    __syncthreads();
    const float inv_n = 1.0f / sqrtf(sm[0] + sm[1] + sm[2] + sm[3]);

    z[(size_t)b * H + t]       = p0 * inv_n;
    z[(size_t)b * H + 256 + t] = p1 * inv_n;
    z[(size_t)b * H + 512 + t] = p2 * inv_n;
}

// Kernel 3 (fused): one block per row i (0..63). Thread j computes
// logit_ij = dot(z[i], z[j]) * 2 (/TAU), then the block does a masked
// logsumexp over j and the pair partial sum over i<j<64, all in-register/LDS.
// Fixed-order reductions -> deterministic.
__global__ void row_loss_k(const float* __restrict__ z,
                           float* __restrict__ rowloss) {
    const int i = blockIdx.x;   // 0..63
    const int j = threadIdx.x;  // 0..255
    __shared__ float zi[H];
    __shared__ float red[4];

    zi[j]       = z[(size_t)i * H + j];
    zi[j + 256] = z[(size_t)i * H + 256 + j];
    zi[j + 512] = z[(size_t)i * H + 512 + j];
    __syncthreads();

    const float4* __restrict__ zj4 = reinterpret_cast<const float4*>(z + (size_t)j * H);
    const float4* zi4 = reinterpret_cast<const float4*>(zi);
    float d = 0.f;
#pragma unroll 8
    for (int k = 0; k < H / 4; ++k) {
        float4 a = zi4[k];
        float4 c = zj4[k];
        d += a.x * c.x + a.y * c.y + a.z * c.z + a.w * c.w;
    }
    const float logit = d * 2.0f;                 // / TAU
    const float x = (j == i) ? -INFINITY : logit;

    // block max
    float m = waveReduceMax(x);
    if ((j & 63) == 0) red[j >> 6] = m;
    __syncthreads();
    m = fmaxf(fmaxf(red[0], red[1]), fmaxf(red[2], red[3]));
    __syncthreads();

    // block sum of exp
    const float e = (j == i) ? 0.f : expf(x - m);
    float s = waveReduceSum(e);
    if ((j & 63) == 0) red[j >> 6] = s;
    __syncthreads();
    const float logden = logf(red[0] + red[1] + red[2] + red[3]) + m;
    __syncthreads();

    // pair terms for this row: j in (i, 64)
    const float term = (j > i && j < NSMALL) ? (logden - logit) : 0.f;
    float ts = waveReduceSum(term);
    if ((j & 63) == 0) red[j >> 6] = ts;
    __syncthreads();
    if (j == 0) rowloss[i] = red[0] + red[1] + red[2] + red[3];
}

// Kernel 4: single wave sums the 64 row losses and applies final scaling.
__global__ void final_k(const float* __restrict__ rowloss,
                        float* __restrict__ out) {
    const int t = threadIdx.x;  // 0..63
    float s = waveReduceSum(rowloss[t]);
    if (t == 0) {
        out[0] = (-2.0f / (float)NSMALL) * (float)(NSMALL - 1) * s;
    }
}

extern "C" void kernel_launch(void* const* d_in, const int* in_sizes, int n_in,
                              void* d_out, int out_size, void* d_ws, size_t ws_size,
                              hipStream_t stream) {
    const float* lhs  = (const float*)d_in[0];   // [256,512,768] f32
    const float* mask = (const float*)d_in[1];   // [256,512] f32
    float* out = (float*)d_out;                  // scalar f32
    float* ws  = (float*)d_ws;

    float* part    = ws;                            // NCH*B*H = 1,572,864 f
    float* z       = part + (size_t)NCH * B * H;    // B*H     =   196,608 f
    float* rowloss = z + (size_t)B * H;             // NSMALL  =        64 f

    pool_partial_k<<<dim3(B, NCH), 192, 0, stream>>>(lhs, part);
    pool_norm_k<<<B, 256, 0, stream>>>(part, mask, z);
    row_loss_k<<<NSMALL, 256, 0, stream>>>(z, rowloss);
    final_k<<<1, 64, 0, stream>>>(rowloss, out);
}

// Round 3
// 95.851 us; speedup vs baseline: 1.7161x; 1.1143x over previous
//
#include <hip/hip_runtime.h>
#include <math.h>

#define B 256
#define S 512
#define H 768
#define NCH 16
#define SCH (S / NCH)   // 32 tokens per chunk
#define NSMALL 64       // n = B/4

__device__ __forceinline__ float waveReduceSum(float v) {
    v += __shfl_down(v, 32);
    v += __shfl_down(v, 16);
    v += __shfl_down(v, 8);
    v += __shfl_down(v, 4);
    v += __shfl_down(v, 2);
    v += __shfl_down(v, 1);
    return v;
}

// Kernel 1: partial token-sum per (batch, s-chunk). 192 threads = 192 float4
// columns covering H=768. A block streams 32 contiguous rows (96 KB).
__global__ void pool_partial_k(const float* __restrict__ lhs,
                               float* __restrict__ part) {
    const int b = blockIdx.x;   // 0..255
    const int c = blockIdx.y;   // 0..15
    const int t = threadIdx.x;  // 0..191
    const float4* __restrict__ src =
        reinterpret_cast<const float4*>(lhs) + ((size_t)b * S + (size_t)c * SCH) * (H / 4);
    float4 acc = make_float4(0.f, 0.f, 0.f, 0.f);
#pragma unroll 8
    for (int s = 0; s < SCH; ++s) {
        float4 v = src[(size_t)s * (H / 4) + t];
        acc.x += v.x; acc.y += v.y; acc.z += v.z; acc.w += v.w;
    }
    float4* dst = reinterpret_cast<float4*>(part) + ((size_t)c * B + b) * (H / 4);
    dst[t] = acc;
}

// Kernel 2: reduce the 16 partials, divide by mask-sum (faithful to ref),
// L2-normalize the pooled row -> z[b][h]. 768 threads: one per h (12 waves).
__global__ void pool_norm_k(const float* __restrict__ part,
                            const float* __restrict__ mask,
                            float* __restrict__ z) {
    const int b = blockIdx.x;   // 0..255
    const int t = threadIdx.x;  // 0..767
    __shared__ float sm[12];

    // mask.sum over 512 tokens (threads 0..511 contribute)
    float mv = (t < S) ? mask[(size_t)b * S + t] : 0.f;
    float w = waveReduceSum(mv);
    if ((t & 63) == 0) sm[t >> 6] = w;
    __syncthreads();
    float msum = 0.f;
#pragma unroll
    for (int k = 0; k < 12; ++k) msum += sm[k];
    __syncthreads();

    // pooled[h]: sum the 16 chunk partials
    float p = 0.f;
#pragma unroll
    for (int c = 0; c < NCH; ++c) {
        p += part[((size_t)c * B + b) * H + t];
    }
    p *= (1.0f / msum);

    float ws2 = waveReduceSum(p * p);
    if ((t & 63) == 0) sm[t >> 6] = ws2;
    __syncthreads();
    float ssq = 0.f;
#pragma unroll
    for (int k = 0; k < 12; ++k) ssq += sm[k];
    const float inv_n = 1.0f / sqrtf(ssq);

    z[(size_t)b * H + t] = p * inv_n;
}

// Kernel 3: 256 blocks = (row i 0..63) x (col-chunk jc 0..3 of 64 cols).
// Thread t: column col = t&63 (global j = jc*64+col), quarter q = t>>6.
// Each thread computes a 192-elem partial dot; LDS-combine to full dots.
// logits in [-2,2] -> exp without max-subtraction is safe.
// Block writes: sp[i*4+jc] = sum_j exp(logit_ij) (diag masked);
// jc==0 also writes pairneg[i] = sum_{j>i,j<64} (-logit_ij).
__global__ void row_part_k(const float* __restrict__ z,
                           float* __restrict__ sp,
                           float* __restrict__ pairneg) {
    const int i  = blockIdx.x >> 2;
    const int jc = blockIdx.x & 3;
    const int t  = threadIdx.x;    // 0..255
    const int col = t & 63;
    const int q   = t >> 6;
    const int j   = jc * 64 + col;

    __shared__ float zi[H];
    __shared__ float pd[4][64];

    // stage z[i] into LDS
    zi[t]       = z[(size_t)i * H + t];
    zi[t + 256] = z[(size_t)i * H + 256 + t];
    zi[t + 512] = z[(size_t)i * H + 512 + t];
    __syncthreads();

    // partial dot: elems q*192 .. q*192+191 (48 float4)
    const float4* __restrict__ zj4 =
        reinterpret_cast<const float4*>(z + (size_t)j * H) + q * 48;
    const float4* zi4 = reinterpret_cast<const float4*>(zi) + q * 48;
    float d0 = 0.f, d1 = 0.f;
#pragma unroll 8
    for (int k = 0; k < 48; k += 2) {
        float4 a = zi4[k];     float4 cc = zj4[k];
        float4 a2 = zi4[k+1];  float4 c2 = zj4[k+1];
        d0 += a.x * cc.x + a.y * cc.y + a.z * cc.z + a.w * cc.w;
        d1 += a2.x * c2.x + a2.y * c2.y + a2.z * c2.z + a2.w * c2.w;
    }
    pd[q][col] = d0 + d1;
    __syncthreads();

    if (t < 64) {  // wave 0 finalizes
        const float dot = pd[0][col] + pd[1][col] + pd[2][col] + pd[3][col];
        const float logit = dot * 2.0f;  // / TAU
        const float e = (j == i) ? 0.f : __expf(logit) * 0.f + ((j == i) ? 0.f : expf(logit));
        // (expf used once; keep deterministic single path)
        const float ev = (j == i) ? 0.f : expf(logit);
        float s = waveReduceSum(ev);
        if (col == 0) sp[i * 4 + jc] = s;
        if (jc == 0) {
            const float term = (col > i) ? -logit : 0.f;
            float ts = waveReduceSum(term);
            if (col == 0) pairneg[i] = ts;
        }
        (void)e;
    }
}

// Kernel 4: one wave. rowloss_i = (63-i)*log(sum_c sp[i][c]) + pairneg[i].
__global__ void final_k(const float* __restrict__ sp,
                        const float* __restrict__ pairneg,
                        float* __restrict__ out) {
    const int i = threadIdx.x;  // 0..63
    const float s = sp[i * 4] + sp[i * 4 + 1] + sp[i * 4 + 2] + sp[i * 4 + 3];
    const float logden = logf(s);
    const float row = (float)(NSMALL - 1 - i) * logden + pairneg[i];
    float tot = waveReduceSum(row);
    if (i == 0) {
        out[0] = (-2.0f / (float)NSMALL) * (float)(NSMALL - 1) * tot;
    }
}

extern "C" void kernel_launch(void* const* d_in, const int* in_sizes, int n_in,
                              void* d_out, int out_size, void* d_ws, size_t ws_size,
                              hipStream_t stream) {
    const float* lhs  = (const float*)d_in[0];   // [256,512,768] f32
    const float* mask = (const float*)d_in[1];   // [256,512] f32
    float* out = (float*)d_out;                  // scalar f32
    float* ws  = (float*)d_ws;

    float* part    = ws;                              // NCH*B*H = 3,145,728 f
    float* z       = part + (size_t)NCH * B * H;      // B*H     =   196,608 f
    float* sp      = z + (size_t)B * H;               // 64*4    =       256 f
    float* pairneg = sp + NSMALL * 4;                 // 64 f

    pool_partial_k<<<dim3(B, NCH), 192, 0, stream>>>(lhs, part);
    pool_norm_k<<<B, H, 0, stream>>>(part, mask, z);
    row_part_k<<<NSMALL * 4, 256, 0, stream>>>(z, sp, pairneg);
    final_k<<<1, 64, 0, stream>>>(sp, pairneg, out);
}

// Round 4
// 84.968 us; speedup vs baseline: 1.9359x; 1.1281x over previous
//
#include <hip/hip_runtime.h>
#include <math.h>

#define B 256
#define S 512
#define H 768
#define H4 (H / 4)      // 192 float4 columns
#define NSMALL 64       // n = B/4

__device__ __forceinline__ float waveReduceSum(float v) {
    v += __shfl_down(v, 32);
    v += __shfl_down(v, 16);
    v += __shfl_down(v, 8);
    v += __shfl_down(v, 4);
    v += __shfl_down(v, 2);
    v += __shfl_down(v, 1);
    return v;
}

// Kernel 1: one block per batch. 768 threads = 192 float4-cols x 4 row-groups.
// Streams the batch's 512x768 slab (1.57 MB) coalesced (each wave: 1 KB
// contiguous per load), LDS-reduces the 4 row-groups, applies mask-sum
// division and L2 normalization in-block, writes z[b] directly.
// No partials buffer, no second pooling kernel.
__global__ void pool_z_k(const float* __restrict__ lhs,
                         const float* __restrict__ mask,
                         float* __restrict__ z) {
    const int b = blockIdx.x;       // 0..255
    const int t = threadIdx.x;      // 0..767
    const int col = t % H4;         // float4 column
    const int rg  = t / H4;         // row-group 0..3 (wave-aligned: 192 = 3*64)

    __shared__ float4 red[3][H4];   // rg 1..3 partials
    __shared__ float sm[12];        // mask wave sums
    __shared__ float sq[3];         // sumsq wave sums

    const float4* __restrict__ src =
        reinterpret_cast<const float4*>(lhs) + (size_t)b * S * H4;
    float4 acc = make_float4(0.f, 0.f, 0.f, 0.f);
#pragma unroll 8
    for (int s = 0; s < S / 4; ++s) {
        float4 v = src[(size_t)(4 * s + rg) * H4 + col];
        acc.x += v.x; acc.y += v.y; acc.z += v.z; acc.w += v.w;
    }
    if (rg > 0) red[rg - 1][col] = acc;

    // mask.sum over 512 tokens (threads 0..511; waves 8..11 contribute 0)
    float mv = (t < S) ? mask[(size_t)b * S + t] : 0.f;
    float w = waveReduceSum(mv);
    if ((t & 63) == 0) sm[t >> 6] = w;
    __syncthreads();

    float msum = 0.f;
#pragma unroll
    for (int k = 0; k < 12; ++k) msum += sm[k];

    float4 p = acc;
    if (rg == 0) {
        float4 r0 = red[0][col], r1 = red[1][col], r2 = red[2][col];
        p.x += r0.x + r1.x + r2.x;
        p.y += r0.y + r1.y + r2.y;
        p.z += r0.z + r1.z + r2.z;
        p.w += r0.w + r1.w + r2.w;
        const float inv_m = 1.0f / msum;
        p.x *= inv_m; p.y *= inv_m; p.z *= inv_m; p.w *= inv_m;
        float s2 = p.x * p.x + p.y * p.y + p.z * p.z + p.w * p.w;
        float ws2 = waveReduceSum(s2);          // waves 0..2 full
        if ((t & 63) == 0) sq[t >> 6] = ws2;
    }
    __syncthreads();
    if (rg == 0) {
        const float inv_n = 1.0f / sqrtf(sq[0] + sq[1] + sq[2]);
        float4 zp = make_float4(p.x * inv_n, p.y * inv_n, p.z * inv_n, p.w * inv_n);
        reinterpret_cast<float4*>(z + (size_t)b * H)[col] = zp;
    }
}

// Kernel 2: 256 blocks = (row i 0..63) x (col-chunk jc 0..3 of 64 cols).
// Thread t: column col = t&63 (global j = jc*64+col), quarter q = t>>6.
// Each thread computes a 192-elem partial dot; LDS-combine to full dots.
// logits in [-2,2] -> exp without max-subtraction is safe (sum <= 255*e^2).
// Block writes: sp[i*4+jc] = sum_j exp(logit_ij) (diag masked);
// jc==0 also writes pairneg[i] = sum_{j>i,j<64} (-logit_ij).
__global__ void row_part_k(const float* __restrict__ z,
                           float* __restrict__ sp,
                           float* __restrict__ pairneg) {
    const int i  = blockIdx.x >> 2;
    const int jc = blockIdx.x & 3;
    const int t  = threadIdx.x;    // 0..255
    const int col = t & 63;
    const int q   = t >> 6;
    const int j   = jc * 64 + col;

    __shared__ float zi[H];
    __shared__ float pd[4][64];

    zi[t]       = z[(size_t)i * H + t];
    zi[t + 256] = z[(size_t)i * H + 256 + t];
    zi[t + 512] = z[(size_t)i * H + 512 + t];
    __syncthreads();

    // partial dot: elems q*192 .. q*192+191 (48 float4)
    const float4* __restrict__ zj4 =
        reinterpret_cast<const float4*>(z + (size_t)j * H) + q * 48;
    const float4* zi4 = reinterpret_cast<const float4*>(zi) + q * 48;
    float d0 = 0.f, d1 = 0.f;
#pragma unroll 8
    for (int k = 0; k < 48; k += 2) {
        float4 a  = zi4[k];     float4 c1 = zj4[k];
        float4 a2 = zi4[k + 1]; float4 c2 = zj4[k + 1];
        d0 += a.x * c1.x + a.y * c1.y + a.z * c1.z + a.w * c1.w;
        d1 += a2.x * c2.x + a2.y * c2.y + a2.z * c2.z + a2.w * c2.w;
    }
    pd[q][col] = d0 + d1;
    __syncthreads();

    if (t < 64) {  // wave 0 finalizes
        const float dot = pd[0][col] + pd[1][col] + pd[2][col] + pd[3][col];
        const float logit = dot * 2.0f;  // / TAU
        const float ev = (j == i) ? 0.f : expf(logit);
        float s = waveReduceSum(ev);
        if (col == 0) sp[i * 4 + jc] = s;
        if (jc == 0) {
            const float term = (col > i) ? -logit : 0.f;
            float ts = waveReduceSum(term);
            if (col == 0) pairneg[i] = ts;
        }
    }
}

// Kernel 3: one wave. rowloss_i = (63-i)*log(sum_c sp[i][c]) + pairneg[i].
__global__ void final_k(const float* __restrict__ sp,
                        const float* __restrict__ pairneg,
                        float* __restrict__ out) {
    const int i = threadIdx.x;  // 0..63
    const float s = sp[i * 4] + sp[i * 4 + 1] + sp[i * 4 + 2] + sp[i * 4 + 3];
    const float logden = logf(s);
    const float row = (float)(NSMALL - 1 - i) * logden + pairneg[i];
    float tot = waveReduceSum(row);
    if (i == 0) {
        out[0] = (-2.0f / (float)NSMALL) * (float)(NSMALL - 1) * tot;
    }
}

extern "C" void kernel_launch(void* const* d_in, const int* in_sizes, int n_in,
                              void* d_out, int out_size, void* d_ws, size_t ws_size,
                              hipStream_t stream) {
    const float* lhs  = (const float*)d_in[0];   // [256,512,768] f32
    const float* mask = (const float*)d_in[1];   // [256,512] f32
    float* out = (float*)d_out;                  // scalar f32
    float* ws  = (float*)d_ws;

    float* z       = ws;                         // B*H = 196,608 f
    float* sp      = z + (size_t)B * H;          // 64*4 = 256 f
    float* pairneg = sp + NSMALL * 4;            // 64 f

    pool_z_k<<<B, H, 0, stream>>>(lhs, mask, z);
    row_part_k<<<NSMALL * 4, 256, 0, stream>>>(z, sp, pairneg);
    final_k<<<1, 64, 0, stream>>>(sp, pairneg, out);
}